// Round 8
// baseline (1114.659 us; speedup 1.0000x reference)
//
#include <hip/hip_runtime.h>

// VQ-VAE quantization: N=32768, K=4096, D=256, fp32.
// Outputs (concat float32): z_q [N*D], idx [N] (as float), one_hot [N*K].
//
// Round-14: 2-plane main pass + exact MFMA fixup.
// Surviving invariant (r7/r9/r12/r13): per-CU B-delivery pinned at ~13.2 B/cyc
// (L1 miss path); each escr byte is read once per CU -> only byte-reduction
// helps. Drop the l-plane from the sweep (products hh,hm,mh,mm): BM=128 fits
// LDS (128KB A) -> 256 blocks, ONE round, 4.19MB/block; B-delivery (132us) and
// MFMA floor (132us) balance. Exactness: |d4-d6| <= 2^-14 Sum|z||e| ~ 0.018;
// rows with runner-up gap <= THR=0.05 (expect ~120) are fully recomputed by a
// fixup kernel using r12's 6-product MFMA chain (bit-identical to the
// previously-passing kernel); winners merged via lex-packed u64 atomicMin.

#define N_TOK 32768
#define K_CODE 4096
#define D_DIM 256
#define BM 128
#define THR_AMBIG 0.05f

typedef float f32x4 __attribute__((ext_vector_type(4)));
typedef short s16x8 __attribute__((ext_vector_type(8)));

// scratch in out[] tail (floats): escr ushort[3*K*D] (=1,572,864 f), e2[K],
// list[8192], amin u64[8192] (=16,384 f), cnt pad[64].
#define OUT_FLOATS 142639104u          // N*D + N + N*K
#define EFRAG_SHORTS (3u * K_CODE * D_DIM)
#define SCR_FLOATS (EFRAG_SHORTS / 2 + K_CODE + 8192u + 16384u + 64u) // 1,601,600
#define SCR_OFF    (OUT_FLOATS - SCR_FLOATS)
#define E2_OFF     (SCR_OFF + EFRAG_SHORTS / 2)
#define LIST_OFF   (E2_OFF + K_CODE)
#define AMIN_OFF   (LIST_OFF + 8192u)
#define CNT_OFF    (AMIN_OFF + 16384u)
#define OH_SAFE_ROWS 32256             // rows >= this: one_hot deferred to vq_oh_tail

#define MFMA(a, b, c) __builtin_amdgcn_mfma_f32_16x16x32_bf16((a), (b), (c), 0, 0, 0)

static __device__ __forceinline__ unsigned short f2bf(float f) {
    unsigned int u = __float_as_uint(f);
    u = (u + 0x7fffu + ((u >> 16) & 1u)) >> 16;
    return (unsigned short)u;
}
static __device__ __forceinline__ float bf2f(unsigned short b) {
    return __uint_as_float(((unsigned int)b) << 16);
}
static __device__ __forceinline__ unsigned long long packvi(float v, int code) {
    unsigned int u = __float_as_uint(v);
    u = (u & 0x80000000u) ? ~u : (u ^ 0x80000000u);   // order-preserving
    return ((unsigned long long)u << 32) | (unsigned int)code;
}

// ---------------------------------------------------------------------------
// Prep: embed -> fragment-ordered bf16 h/m/l planes + e2; init cnt/amin.
// Frag layout (1KB): [ct_g(256)][dc(8)][c(3)][lane(64)][8 bf16].
// ---------------------------------------------------------------------------
__global__ __launch_bounds__(256) void vq_prep(const float* __restrict__ embed,
                                               float* __restrict__ out) {
    __shared__ float part[8][33];
    unsigned short* escr = (unsigned short*)(out + SCR_OFF);
    float* e2g = out + E2_OFF;

    const int t    = threadIdx.x;
    const int cl   = t >> 5;
    const int r32  = t & 31;
    const int dc   = r32 >> 2;
    const int quad = r32 & 3;
    const int k    = blockIdx.x * 8 + cl;

    if (blockIdx.x == 0) {                      // re-init fixup state every launch
        if (t == 0) ((int*)(out + CNT_OFF))[0] = 0;
        unsigned long long* am = (unsigned long long*)(out + AMIN_OFF);
        for (int i = t; i < 8192; i += 256) am[i] = ~0ull;
    }

    const float* src = embed + (size_t)k * D_DIM + dc * 32 + quad * 8;
    float x[8];
    *(float4*)(x)     = *(const float4*)(src);
    *(float4*)(x + 4) = *(const float4*)(src + 4);

    s16x8 hv, mv, lv;
    float s2 = 0.0f;
#pragma unroll
    for (int j = 0; j < 8; ++j) {
        const float xx = x[j];
        s2 += xx * xx;
        const unsigned short bh = f2bf(xx);
        const float r1 = xx - bf2f(bh);
        const unsigned short bm = f2bf(r1);
        hv[j] = (short)bh; mv[j] = (short)bm; lv[j] = (short)f2bf(r1 - bf2f(bm));
    }

    const int ct_g = k >> 4;
    const int lane = quad * 16 + (k & 15);
    const size_t base = ((size_t)(ct_g * 8 + dc) * 3) * 512 + lane * 8;
    *(s16x8*)&escr[base]        = hv;
    *(s16x8*)&escr[base + 512]  = mv;
    *(s16x8*)&escr[base + 1024] = lv;

    part[cl][r32] = s2;
    __syncthreads();
    if (t < 8) {
        float s = 0.0f;
#pragma unroll
        for (int j = 0; j < 32; ++j) s += part[t][j];   // fixed order: deterministic
        e2g[blockIdx.x * 8 + t] = s;
    }
}

// ---------------------------------------------------------------------------
// Pass 1: BM=128 rows/block, 2-plane (h,m), 256 blocks = 1 round.
// 128 steps = (ctile 0..15 of 256 codes) x (dc 0..7); u=2 per wave; per-slot
// (v1,i1,v2) lex tracking; ambiguous rows appended to global list.
// ---------------------------------------------------------------------------
__global__ __launch_bounds__(512, 2)
void vq_pass1(const float* __restrict__ z_e,
              const float* __restrict__ embed,
              float* __restrict__ out) {
    __shared__ __align__(16) short As[65536];   // 128KB: [(c*8+rt)*8+dc]*512 + ls*8
    __shared__ float redv1[128][9];
    __shared__ int   redi1[128][9];
    __shared__ float redv2[128][9];
    __shared__ int   bk_lds[128];

    const unsigned short* escr = (const unsigned short*)(out + SCR_OFF);
    const float* e2g = out + E2_OFF;
    int* list = (int*)(out + LIST_OFF);
    int* cnt  = (int*)(out + CNT_OFF);

    const int t    = threadIdx.x;
    const int w    = t >> 6;
    const int lane = t & 63;
    const int n    = lane & 15;
    const int quad = lane >> 4;
    const int row0 = blockIdx.x * BM;

    // ---- stage + convert A (h,m only) ----
#pragma unroll
    for (int i = 0; i < 8; ++i) {
        const int run  = t + 512 * i;           // (row, dcs, qs): 128*8*4 = 4096
        const int qs   = run & 3;
        const int dcs  = (run >> 2) & 7;
        const int row  = run >> 5;
        const float* src = z_e + (size_t)(row0 + row) * D_DIM + dcs * 32 + qs * 8;
        float x[8];
        *(float4*)(x)     = *(const float4*)(src);
        *(float4*)(x + 4) = *(const float4*)(src + 4);
        s16x8 hv, mv;
#pragma unroll
        for (int j = 0; j < 8; ++j) {
            const float xx = x[j];
            const unsigned short bh = f2bf(xx);
            hv[j] = (short)bh;
            mv[j] = (short)f2bf(xx - bf2f(bh));
        }
        const int rt = row >> 4;
        const int ls = qs * 16 + (row & 15);
        *(s16x8*)&As[((0 * 8 + rt) * 8 + dcs) * 512 + ls * 8] = hv;
        *(s16x8*)&As[((1 * 8 + rt) * 8 + dcs) * 512 + ls * 8] = mv;
    }
    __syncthreads();

    float bv1[32]; int bi1[32]; float bv2[32];
#pragma unroll
    for (int s = 0; s < 32; ++s) { bv1[s] = 3.0e38f; bi1[s] = 0x7fffffff; bv2[s] = 3.0e38f; }

    f32x4 acc[8][2];
#pragma unroll
    for (int rt = 0; rt < 8; ++rt)
#pragma unroll
        for (int u = 0; u < 2; ++u) acc[rt][u] = (f32x4){0.f, 0.f, 0.f, 0.f};

    float e2r[2];
    s16x8 B0[2][2], B1[2][2];                    // [u][c], c in {h,m}

    // escr shorts offset: ct_g*12288 + dc*1536 + c*512 + lane*8; ct_g = ctile*16 + wu*2 + u
    const int wu = __builtin_amdgcn_readfirstlane(w);
    const unsigned short* ebase = escr + (size_t)(wu * 2) * 12288 + lane * 8;

    // boff(s): s = ctile*8 + dc
#define P1OFF(s) ((size_t)((s) >> 3) * 196608 + (size_t)((s) & 7) * 1536)
#define LOADB2(buf, p)                                         \
    {                                                          \
        _Pragma("unroll") for (int u = 0; u < 2; ++u)          \
            _Pragma("unroll") for (int c = 0; c < 2; ++c)      \
                (buf)[u][c] = *(const s16x8*)((p) + u * 12288 + c * 512); \
    }

    LOADB2(B0, ebase)                            // step 0

#define PROC1(s, B)                                                            \
    {                                                                          \
        const int ctile = (s) >> 3, dc = (s) & 7;                              \
        if (dc == 0) {                                                         \
            _Pragma("unroll") for (int u = 0; u < 2; ++u)                      \
                e2r[u] = e2g[ctile * 256 + (wu * 2 + u) * 16 + n];             \
        }                                                                      \
        _Pragma("unroll") for (int rt = 0; rt < 8; ++rt) {                     \
            s16x8 af0 = *(const s16x8*)&As[((0 * 8 + rt) * 8 + dc) * 512 + lane * 8]; \
            s16x8 af1 = *(const s16x8*)&As[((1 * 8 + rt) * 8 + dc) * 512 + lane * 8]; \
            _Pragma("unroll") for (int u = 0; u < 2; ++u) {                    \
                f32x4 a = acc[rt][u];                                          \
                a = MFMA(af0, B[u][0], a);                                     \
                a = MFMA(af0, B[u][1], a);                                     \
                a = MFMA(af1, B[u][0], a);                                     \
                a = MFMA(af1, B[u][1], a);                                     \
                acc[rt][u] = a;                                                \
            }                                                                  \
        }                                                                      \
        if (dc == 7) {                                                         \
            _Pragma("unroll") for (int u = 0; u < 2; ++u) {                    \
                const int code = ctile * 256 + (wu * 2 + u) * 16 + n;          \
                _Pragma("unroll") for (int rt = 0; rt < 8; ++rt)               \
                    _Pragma("unroll") for (int r = 0; r < 4; ++r) {            \
                        const float val = fmaf(-2.0f, acc[rt][u][r], e2r[u]);  \
                        const int slot = rt * 4 + r;                           \
                        if (val < bv1[slot] ||                                 \
                            (val == bv1[slot] && code < bi1[slot])) {          \
                            bv2[slot] = bv1[slot];                             \
                            bv1[slot] = val; bi1[slot] = code;                 \
                        } else if (val < bv2[slot]) bv2[slot] = val;           \
                    }                                                          \
            }                                                                  \
            _Pragma("unroll") for (int rt = 0; rt < 8; ++rt)                   \
                _Pragma("unroll") for (int u = 0; u < 2; ++u)                  \
                    acc[rt][u] = (f32x4){0.f, 0.f, 0.f, 0.f};                  \
        }                                                                      \
    }

#pragma unroll 1
    for (int it = 0; it < 64; ++it) {
        const int s0 = it * 2, s1 = s0 + 1, s2 = s0 + 2;
        LOADB2(B1, ebase + P1OFF(s1))
        PROC1(s0, B0)
        if (it < 63) LOADB2(B0, ebase + P1OFF(s2))
        PROC1(s1, B1)
    }

    // butterfly over the 16 lanes of each quad-group: lex (v1,i1) + value v2
#pragma unroll
    for (int slot = 0; slot < 32; ++slot) {
#pragma unroll
        for (int mask = 1; mask < 16; mask <<= 1) {
            const float ov1 = __shfl_xor(bv1[slot], mask);
            const int   oi1 = __shfl_xor(bi1[slot], mask);
            const float ov2 = __shfl_xor(bv2[slot], mask);
            const bool  ol  = ov1 < bv1[slot] || (ov1 == bv1[slot] && oi1 < bi1[slot]);
            const float big = ol ? bv1[slot] : ov1;
            if (ol) { bv1[slot] = ov1; bi1[slot] = oi1; }
            bv2[slot] = fminf(fminf(bv2[slot], ov2), big);
        }
    }
    if (n == 0) {
#pragma unroll
        for (int rt = 0; rt < 8; ++rt)
#pragma unroll
            for (int r = 0; r < 4; ++r) {
                const int rl = rt * 16 + quad * 4 + r;   // C/D: row=quad*4+reg
                const int slot = rt * 4 + r;
                redv1[rl][w] = bv1[slot];
                redi1[rl][w] = bi1[slot];
                redv2[rl][w] = bv2[slot];
            }
    }
    __syncthreads();
    if (t < 128) {
        float v1 = redv1[t][0]; int i1 = redi1[t][0]; float v2 = redv2[t][0];
#pragma unroll
        for (int j = 1; j < 8; ++j) {
            const float b1 = redv1[t][j]; const int bi = redi1[t][j];
            const float b2 = redv2[t][j];
            const bool  bl = b1 < v1 || (b1 == v1 && bi < i1);
            const float big = bl ? v1 : b1;
            if (bl) { v1 = b1; i1 = bi; }
            v2 = fminf(fminf(v2, b2), big);
        }
        bk_lds[t] = i1;
        out[(size_t)N_TOK * D_DIM + (size_t)(row0 + t)] = (float)i1;
        if (v2 - v1 <= THR_AMBIG) {              // ambiguous under 2-plane error bound
            const int pos = atomicAdd(cnt, 1);
            if (pos < 8192) list[pos] = row0 + t;
        }
    }
    __syncthreads();

    // ---- fused output tail ----
    float* zq = out;
    float* oh = out + (size_t)N_TOK * D_DIM + N_TOK;

#pragma unroll 1
    for (int rr = 0; rr < 16; ++rr) {           // z_q: wave w owns rows w*16..+15
        const int rl  = w * 16 + rr;
        const int row = row0 + rl;
        const int bk  = bk_lds[rl];
        f32x4 v = *(const f32x4*)&embed[(size_t)bk * D_DIM + lane * 4];
        __builtin_nontemporal_store(v, (f32x4*)&zq[(size_t)row * D_DIM + lane * 4]);
    }
    if (row0 < OH_SAFE_ROWS) {                  // blocks 252..255 deferred to oh_tail
#pragma unroll 1
        for (int rr = 0; rr < 16; ++rr) {
            const int rl  = w * 16 + rr;
            const int row = row0 + rl;
            const int bk  = bk_lds[rl];
            float* ohrow = &oh[(size_t)row * K_CODE];
#pragma unroll
            for (int g = 0; g < 16; ++g) {
                const int base = (g * 64 + lane) * 4;
                f32x4 u;
                u.x = (bk == base    ) ? 1.0f : 0.0f;
                u.y = (bk == base + 1) ? 1.0f : 0.0f;
                u.z = (bk == base + 2) ? 1.0f : 0.0f;
                u.w = (bk == base + 3) ? 1.0f : 0.0f;
                __builtin_nontemporal_store(u, (f32x4*)&ohrow[base]);
            }
        }
    }
}

// ---------------------------------------------------------------------------
// Fixup A: exact 6-product recompute for listed rows (bit-identical to the
// r12 chain). Grid 16 = 8 code-slices x 2 row-chunk strides; each block
// gathers <=64 rows, sweeps its 512-code slice (8 dc steps), merges per-row
// (v,i) and atomicMin's a lex-packed u64.
// ---------------------------------------------------------------------------
__global__ __launch_bounds__(512, 2)
void vq_fixa(const float* __restrict__ z_e, float* __restrict__ out) {
    __shared__ __align__(16) short As[49152];   // 96KB, r12 layout
    __shared__ float redv[64][9];
    __shared__ int   redi[64][9];
    __shared__ int   rows_lds[64];

    const unsigned short* escr = (const unsigned short*)(out + SCR_OFF);
    const float* e2g = out + E2_OFF;
    const int* list = (const int*)(out + LIST_OFF);
    unsigned long long* amin = (unsigned long long*)(out + AMIN_OFF);
    const int cntv = ((const int*)(out + CNT_OFF))[0];
    const int ncap = cntv < 8192 ? cntv : 8192;
    if (ncap <= 0) return;

    const int t    = threadIdx.x;
    const int w    = t >> 6;
    const int lane = t & 63;
    const int n    = lane & 15;
    const int quad = lane >> 4;
    const int slice = blockIdx.x & 7;            // ktp 0..7 (512 codes each)
    const int c0    = blockIdx.x >> 3;

    const int wu = __builtin_amdgcn_readfirstlane(w);
    const unsigned short* ebase = escr + (size_t)wu * 49152 + lane * 8;

#pragma unroll 1
    for (int chunk = c0; chunk * 64 < ncap; chunk += 2) {
        const int nrows = (ncap - chunk * 64) < 64 ? (ncap - chunk * 64) : 64;
        if (t < 64) {
            const int j = chunk * 64 + t;
            rows_lds[t] = list[j < ncap ? j : chunk * 64];   // pad = dup row
        }
        __syncthreads();

        // gather-stage + convert A (3 planes, 64 rows)
#pragma unroll
        for (int i = 0; i < 4; ++i) {
            const int run  = t + 512 * i;
            const int qs   = run & 3;
            const int dcs  = (run >> 2) & 7;
            const int row  = run >> 5;
            const int grow = rows_lds[row];
            const float* src = z_e + (size_t)grow * D_DIM + dcs * 32 + qs * 8;
            float x[8];
            *(float4*)(x)     = *(const float4*)(src);
            *(float4*)(x + 4) = *(const float4*)(src + 4);
            s16x8 hv, mv, lv;
#pragma unroll
            for (int j = 0; j < 8; ++j) {
                const float xx = x[j];
                const unsigned short bh = f2bf(xx);
                const float r1 = xx - bf2f(bh);
                const unsigned short bm = f2bf(r1);
                hv[j] = (short)bh; mv[j] = (short)bm; lv[j] = (short)f2bf(r1 - bf2f(bm));
            }
            const int rt = row >> 4;
            const int ls = qs * 16 + (row & 15);
            *(s16x8*)&As[((0 * 4 + rt) * 8 + dcs) * 512 + ls * 8] = hv;
            *(s16x8*)&As[((1 * 4 + rt) * 8 + dcs) * 512 + ls * 8] = mv;
            *(s16x8*)&As[((2 * 4 + rt) * 8 + dcs) * 512 + ls * 8] = lv;
        }
        __syncthreads();

        float bv[16]; int bidx[16];
#pragma unroll
        for (int s = 0; s < 16; ++s) { bv[s] = 3.0e38f; bidx[s] = 0x7fffffff; }
        f32x4 acc[4][4];
#pragma unroll
        for (int rt = 0; rt < 4; ++rt)
#pragma unroll
            for (int u = 0; u < 4; ++u) acc[rt][u] = (f32x4){0.f, 0.f, 0.f, 0.f};
        float e2r[4];

#pragma unroll 1
        for (int dc = 0; dc < 8; ++dc) {         // single-buffered: tiny sweep
            s16x8 B[4][3];
            const unsigned short* p = ebase + (size_t)slice * 393216 + (size_t)dc * 1536;
#pragma unroll
            for (int u = 0; u < 4; ++u)
#pragma unroll
                for (int c = 0; c < 3; ++c)
                    B[u][c] = *(const s16x8*)(p + u * 12288 + c * 512);
            if (dc == 0) {
#pragma unroll
                for (int u = 0; u < 4; ++u)
                    e2r[u] = e2g[slice * 512 + (wu * 4 + u) * 16 + n];
            }
#pragma unroll
            for (int rt = 0; rt < 4; ++rt) {
                s16x8 af0 = *(const s16x8*)&As[((0 * 4 + rt) * 8 + dc) * 512 + lane * 8];
                s16x8 af1 = *(const s16x8*)&As[((1 * 4 + rt) * 8 + dc) * 512 + lane * 8];
                s16x8 af2 = *(const s16x8*)&As[((2 * 4 + rt) * 8 + dc) * 512 + lane * 8];
#pragma unroll
                for (int u = 0; u < 4; ++u) {
                    f32x4 a = acc[rt][u];
                    a = MFMA(af0, B[u][0], a);   // hh
                    a = MFMA(af0, B[u][1], a);   // hm
                    a = MFMA(af1, B[u][0], a);   // mh
                    a = MFMA(af1, B[u][1], a);   // mm
                    a = MFMA(af0, B[u][2], a);   // hl
                    a = MFMA(af2, B[u][0], a);   // lh
                    acc[rt][u] = a;
                }
            }
        }
#pragma unroll
        for (int u = 0; u < 4; ++u) {
            const int code = slice * 512 + (wu * 4 + u) * 16 + n;
#pragma unroll
            for (int rt = 0; rt < 4; ++rt)
#pragma unroll
                for (int r = 0; r < 4; ++r) {
                    const float val = fmaf(-2.0f, acc[rt][u][r], e2r[u]);
                    const int slot = rt * 4 + r;
                    if (val < bv[slot] || (val == bv[slot] && code < bidx[slot])) {
                        bv[slot] = val; bidx[slot] = code;
                    }
                }
        }
#pragma unroll
        for (int slot = 0; slot < 16; ++slot) {
#pragma unroll
            for (int mask = 1; mask < 16; mask <<= 1) {
                const float ov = __shfl_xor(bv[slot], mask);
                const int   oi = __shfl_xor(bidx[slot], mask);
                if (ov < bv[slot] || (ov == bv[slot] && oi < bidx[slot])) {
                    bv[slot] = ov; bidx[slot] = oi;
                }
            }
        }
        if (n == 0) {
#pragma unroll
            for (int rt = 0; rt < 4; ++rt)
#pragma unroll
                for (int r = 0; r < 4; ++r) {
                    const int rl = rt * 16 + quad * 4 + r;
                    redv[rl][w] = bv[rt * 4 + r];
                    redi[rl][w] = bidx[rt * 4 + r];
                }
        }
        __syncthreads();
        if (t < nrows) {
            float v = redv[t][0]; int bi = redi[t][0];
#pragma unroll
            for (int j = 1; j < 8; ++j) {
                const float v2 = redv[t][j]; const int i2 = redi[t][j];
                if (v2 < v || (v2 == v && i2 < bi)) { v = v2; bi = i2; }
            }
            atomicMin(&amin[chunk * 64 + t], packvi(v, bi));
        }
        __syncthreads();
    }
}

// ---------------------------------------------------------------------------
// Fixup B: apply corrected winners (idx, z_q row, one_hot 2-entry flip).
// ---------------------------------------------------------------------------
__global__ __launch_bounds__(256) void vq_fixb(const float* __restrict__ embed,
                                               float* __restrict__ out) {
    const int* list = (const int*)(out + LIST_OFF);
    const unsigned long long* amin = (const unsigned long long*)(out + AMIN_OFF);
    const int cntv = ((const int*)(out + CNT_OFF))[0];
    const int ncap = cntv < 8192 ? cntv : 8192;

    float* idxf = out + (size_t)N_TOK * D_DIM;
    float* zq   = out;
    float* oh   = out + (size_t)N_TOK * D_DIM + N_TOK;
    const int t = threadIdx.x;

#pragma unroll 1
    for (int e = blockIdx.x; e < ncap; e += 32) {
        const int row = list[e];
        const int bi  = (int)(amin[e] & 0xffffffffu) & (K_CODE - 1);
        const int io  = ((int)idxf[row]) & (K_CODE - 1);
        if (bi != io) {
            if (t == 0) idxf[row] = (float)bi;
            if (t < 64) {
                f32x4 v = *(const f32x4*)&embed[(size_t)bi * D_DIM + t * 4];
                *(f32x4*)&zq[(size_t)row * D_DIM + t * 4] = v;
            }
            if (row < OH_SAFE_ROWS && t == 0) {
                oh[(size_t)row * K_CODE + io] = 0.0f;
                oh[(size_t)row * K_CODE + bi] = 1.0f;
            }
        }
    }
}

// ---------------------------------------------------------------------------
// Cleanup: one_hot for rows 32256..32767 (scratch overlap region). Runs last,
// reads final (fixed) idx.
// ---------------------------------------------------------------------------
__launch_bounds__(256, 8)
__global__ void vq_oh_tail(float* __restrict__ out) {
    __shared__ int bks[16];
    const int t    = threadIdx.x;
    const int w    = t >> 6;
    const int lane = t & 63;
    const int row0 = OH_SAFE_ROWS + blockIdx.x * 16;

    const float* idxf = out + (size_t)N_TOK * D_DIM;
    float* oh = out + (size_t)N_TOK * D_DIM + N_TOK;

    if (t < 16) bks[t] = ((int)idxf[row0 + t]) & (K_CODE - 1);
    __syncthreads();

#pragma unroll 1
    for (int rr = 0; rr < 4; ++rr) {
        const int r   = rr * 4 + w;
        const int row = row0 + r;
        const int bk  = bks[r];
        float* ohrow = &oh[(size_t)row * K_CODE];
#pragma unroll
        for (int g = 0; g < 16; ++g) {
            const int base = (g * 64 + lane) * 4;
            f32x4 u;
            u.x = (bk == base    ) ? 1.0f : 0.0f;
            u.y = (bk == base + 1) ? 1.0f : 0.0f;
            u.z = (bk == base + 2) ? 1.0f : 0.0f;
            u.w = (bk == base + 3) ? 1.0f : 0.0f;
            __builtin_nontemporal_store(u, (f32x4*)&ohrow[base]);
        }
    }
}

extern "C" void kernel_launch(void* const* d_in, const int* in_sizes, int n_in,
                              void* d_out, int out_size, void* d_ws, size_t ws_size,
                              hipStream_t stream) {
    const float* z_e   = (const float*)d_in[0];
    const float* embed = (const float*)d_in[1];
    float* out = (float*)d_out;

    hipLaunchKernelGGL(vq_prep,    dim3(K_CODE / 8), dim3(256), 0, stream, embed, out);
    hipLaunchKernelGGL(vq_pass1,   dim3(N_TOK / BM), dim3(512), 0, stream, z_e, embed, out);
    hipLaunchKernelGGL(vq_fixa,    dim3(16),  dim3(512), 0, stream, z_e, out);
    hipLaunchKernelGGL(vq_fixb,    dim3(32),  dim3(256), 0, stream, embed, out);
    hipLaunchKernelGGL(vq_oh_tail, dim3((N_TOK - OH_SAFE_ROWS) / 16), dim3(256), 0, stream, out);
}